// Round 4
// baseline (194.420 us; speedup 1.0000x reference)
//
#include <hip/hip_runtime.h>

#define EMB   300
#define QLEN  256
#define DLEN  8192
#define KTOP  5
#define STR   320      // bf16 row stride (elements)
#define STRB  640      // bf16 row stride (bytes)

typedef __attribute__((ext_vector_type(8))) short short8v;
typedef __attribute__((ext_vector_type(4))) float f32x4;

__device__ inline float bf2f(short u) {
    return __uint_as_float(((unsigned int)(unsigned short)u) << 16);
}
__device__ inline short f2bf(float f) {
    unsigned int x = __float_as_uint(f);
    unsigned int r = x + 0x7fffu + ((x >> 16) & 1u);  // RNE
    return (short)(r >> 16);
}
__device__ inline void gload_lds16(const void* g, void* l) {
    __builtin_amdgcn_global_load_lds((const __attribute__((address_space(1))) void*)g,
                                     (__attribute__((address_space(3))) void*)l, 16, 0, 0);
}
// LDS swizzle involution on an 8KB [128 rows][64B] tile
__device__ inline int swz(int a) { return a ^ (((a >> 7) & 7) << 4); }

// ---------------- batched gather + cast, writes pads ----------------
struct GatherArgs { const int* toks[3]; short* out[3]; int rows[3]; };

__global__ void gather_cast(const float* __restrict__ embeds, GatherArgs ga) {
    int s = blockIdx.y;
    const int* toks = ga.toks[s];
    short* out = ga.out[s];
    int rows = ga.rows[s];
    long total = (long)(rows + 8) * STR;
    for (long idx = blockIdx.x * (long)blockDim.x + threadIdx.x; idx < total;
         idx += (long)gridDim.x * blockDim.x) {
        int r = (int)(idx / STR);
        int e = (int)(idx - (long)r * STR);
        short v = 0;
        if (r < rows && e < EMB) v = f2bf(embeds[(long)toks[r] * EMB + e]);
        out[idx] = v;
    }
}

// ------- batched filter cast: (300,1,fs,300) f32 -> flat [384][fs*320] bf16 -------
struct FiltArgs { const float* f[2]; short* out[2]; int fs[2]; };

__global__ void cast_filt(FiltArgs fa) {
    int s = blockIdx.y;
    const float* f = fa.f[s];
    short* out = fa.out[s];
    int fs = fa.fs[s];
    long total = (long)384 * fs * STR;
    for (long idx = blockIdx.x * (long)blockDim.x + threadIdx.x; idx < total;
         idx += (long)gridDim.x * blockDim.x) {
        int o = (int)(idx / (fs * STR));
        int rem = (int)(idx - (long)o * fs * STR);
        int kh = rem / STR, e = rem - kh * STR;
        short v = 0;
        if (o < EMB && e < EMB) v = f2bf(f[(long)o * fs * EMB + (long)kh * EMB + e]);
        out[idx] = v;
    }
}

// ================= shared pipelined GEMM core (3-deep counted-vmcnt) =================
// 128x128 tile, 4 waves, BK=32 elems (64B). LDS: 3 x (8KB A + 8KB B) = 48KB.

#define GEMM_PRELUDE                                                          \
    int tid = threadIdx.x, lane = tid & 63, w = tid >> 6;                     \
    int wr = w >> 1, wc = w & 1;                                              \
    int ldsoff0 = (2 * w) * 1024, ldsoff1 = (2 * w + 1) * 1024;               \
    int r0_, c0_, r1_, c1_;                                                   \
    { int l0 = swz((2 * w) * 1024 + lane * 16);                               \
      r0_ = l0 >> 6; c0_ = ((l0 >> 4) & 3) * 16;                              \
      int l1 = swz((2 * w + 1) * 1024 + lane * 16);                           \
      r1_ = l1 >> 6; c1_ = ((l1 >> 4) & 3) * 16; }

#define STAGE(t, buf) do { int k0b_ = (t) * 64;                               \
    gload_lds16(Ab + (size_t)r0_ * STRB + c0_ + k0b_, AsB + (buf) * 8192 + ldsoff0); \
    gload_lds16(Ab + (size_t)r1_ * STRB + c1_ + k0b_, AsB + (buf) * 8192 + ldsoff1); \
    gload_lds16(Bb + (size_t)r0_ * ldbB + c0_ + k0b_, BsB + (buf) * 8192 + ldsoff0); \
    gload_lds16(Bb + (size_t)r1_ * ldbB + c1_ + k0b_, BsB + (buf) * 8192 + ldsoff1); \
  } while (0)

#define GSTEP(VM, t, DOST) do {                                               \
    asm volatile("s_waitcnt " VM ::: "memory");                               \
    __builtin_amdgcn_s_barrier();                                             \
    __builtin_amdgcn_sched_barrier(0);                                        \
    { const char* Ac_ = AsB + ((t) % 3) * 8192;                               \
      const char* Bc_ = BsB + ((t) % 3) * 8192;                               \
      short8v a_[4], b_[4];                                                   \
      _Pragma("unroll")                                                       \
      for (int f_ = 0; f_ < 4; ++f_) {                                        \
          int ra_ = wr * 64 + f_ * 16 + (lane & 15);                          \
          int la_ = ra_ * 64 + (lane >> 4) * 16;                              \
          a_[f_] = *(const short8v*)(Ac_ + swz(la_));                         \
          int rb_ = wc * 64 + f_ * 16 + (lane & 15);                          \
          int lb_ = rb_ * 64 + (lane >> 4) * 16;                              \
          b_[f_] = *(const short8v*)(Bc_ + swz(lb_));                         \
      }                                                                       \
      asm volatile("s_waitcnt lgkmcnt(0)" ::: "memory");                      \
      __builtin_amdgcn_sched_barrier(0);                                      \
      _Pragma("unroll")                                                       \
      for (int mf_ = 0; mf_ < 4; ++mf_)                                       \
          _Pragma("unroll")                                                   \
          for (int nf_ = 0; nf_ < 4; ++nf_)                                   \
              acc[mf_][nf_] = __builtin_amdgcn_mfma_f32_16x16x32_bf16(        \
                  a_[mf_], b_[nf_], acc[mf_][nf_], 0, 0, 0);                  \
    }                                                                         \
    __builtin_amdgcn_sched_barrier(0);                                        \
    __builtin_amdgcn_s_barrier();                                             \
    __builtin_amdgcn_sched_barrier(0);                                        \
    if (DOST) { STAGE((t) + 3, (t) % 3); __builtin_amdgcn_sched_barrier(0); } \
  } while (0)

#define GEMM_MAIN(nt) do {                                                    \
    STAGE(0, 0); STAGE(1, 1); STAGE(2, 2);                                    \
    __builtin_amdgcn_sched_barrier(0);                                        \
    for (int t_ = 0; t_ < (nt) - 2; ++t_) GSTEP("vmcnt(8)", t_, t_ + 3 < (nt)); \
    GSTEP("vmcnt(4)", (nt) - 2, false);                                       \
    GSTEP("vmcnt(0)", (nt) - 1, false);                                       \
  } while (0)

// ---------------- conv GEMM (flat-K im2col-free) ----------------
// O[m][n] = bf16(prelu(sum_{k<fs*320} Aflat[(m+shift)*320+k]*F[n][k], a) + A[m][n])
struct ConvSlice { const short* A; const short* F; short* O; const float* alpha; int M; int fs; int shift; };
struct ConvArgs { ConvSlice s[6]; };

__global__ __launch_bounds__(256) void conv_mfma(ConvArgs args) {
    int lin = blockIdx.x;
    int wk = (lin & 7) * 144 + (lin >> 3);   // bijective XCD swizzle (1152 % 8 == 0)
    int x = wk % 3; int rest = wk / 3; int y = rest & 63; int z = rest >> 6;
    ConvSlice sl;
    switch (z) {
        case 0: sl = args.s[0]; break; case 1: sl = args.s[1]; break;
        case 2: sl = args.s[2]; break; case 3: sl = args.s[3]; break;
        case 4: sl = args.s[4]; break; default: sl = args.s[5]; break;
    }
    int m0 = y * 128;
    if (m0 >= sl.M) return;
    int n0 = x * 128;

    __shared__ char AsB[3 * 8192];
    __shared__ char BsB[3 * 8192];
    GEMM_PRELUDE
    float al = *sl.alpha;   // issued before all stages: never breaks vmcnt counting

    const char* Ab = (const char*)sl.A + (size_t)(m0 + sl.shift) * STRB;
    int ldbB = sl.fs * STRB;
    const char* Bb = (const char*)sl.F + (size_t)n0 * ldbB;
    int nt = sl.fs * 10;

    f32x4 acc[4][4] = {};
    GEMM_MAIN(nt);

    #pragma unroll
    for (int mf = 0; mf < 4; ++mf) {
        int r0 = m0 + wr * 64 + mf * 16 + (lane >> 4) * 4;
        #pragma unroll
        for (int nf = 0; nf < 4; ++nf) {
            int c = n0 + wc * 64 + nf * 16 + (lane & 15);
            if (c < STR) {
                #pragma unroll
                for (int j = 0; j < 4; ++j) {
                    int r = r0 + j;
                    short ov = 0;
                    if (c < EMB) {
                        float v = acc[mf][nf][j];
                        v = v >= 0.f ? v : al * v;
                        v += bf2f(sl.A[(size_t)r * STR + c]);
                        ov = f2bf(v);
                    }
                    sl.O[(size_t)r * STR + c] = ov;
                }
            }
        }
    }
}

// ---------------- sim GEMM: C bf16[256][8192] = A[256][320] @ B[8192][320]^T ----------------
struct SimSlice { const short* A; const short* B; short* C; };
struct SimArgs { SimSlice s[6]; };

__global__ __launch_bounds__(256) void sim_mfma(SimArgs args) {
    int lin = blockIdx.x;
    int wk = (lin & 7) * 96 + (lin >> 3);    // bijective XCD swizzle (768 % 8 == 0)
    int y = wk & 1; int x = (wk >> 1) & 63; int z = wk >> 7;
    SimSlice sl;
    switch (z) {
        case 0: sl = args.s[0]; break; case 1: sl = args.s[1]; break;
        case 2: sl = args.s[2]; break; case 3: sl = args.s[3]; break;
        case 4: sl = args.s[4]; break; default: sl = args.s[5]; break;
    }
    int m0 = y * 128;
    int n0 = x * 128;

    __shared__ char AsB[3 * 8192];
    __shared__ char BsB[3 * 8192];
    GEMM_PRELUDE

    const char* Ab = (const char*)sl.A + (size_t)m0 * STRB;
    const int ldbB = STRB;
    const char* Bb = (const char*)sl.B + (size_t)n0 * STRB;

    f32x4 acc[4][4] = {};
    GEMM_MAIN(10);

    #pragma unroll
    for (int mf = 0; mf < 4; ++mf) {
        int r0 = m0 + wr * 64 + mf * 16 + (lane >> 4) * 4;
        #pragma unroll
        for (int nf = 0; nf < 4; ++nf) {
            int c = n0 + wc * 64 + nf * 16 + (lane & 15);
            #pragma unroll
            for (int j = 0; j < 4; ++j)
                sl.C[(size_t)(r0 + j) * DLEN + c] = f2bf(acc[mf][nf][j]);
        }
    }
}

// ---------------- batched row inverse L2 norm from bf16 ----------------
struct InvSlice { const short* X; float* inv; int rows; };
struct InvArgs { InvSlice s[9]; };

__global__ void inv_norms(InvArgs args) {
    InvSlice sl;
    switch (blockIdx.y) {
        case 0: sl = args.s[0]; break; case 1: sl = args.s[1]; break;
        case 2: sl = args.s[2]; break; case 3: sl = args.s[3]; break;
        case 4: sl = args.s[4]; break; case 5: sl = args.s[5]; break;
        case 6: sl = args.s[6]; break; case 7: sl = args.s[7]; break;
        default: sl = args.s[8]; break;
    }
    int row = blockIdx.x * 4 + (threadIdx.x >> 6);
    int lane = threadIdx.x & 63;
    if (row >= sl.rows) return;
    const short* p = sl.X + (size_t)row * STR;
    float s = 0.f;
    for (int e = lane; e < EMB; e += 64) { float v = bf2f(p[e]); s += v * v; }
    #pragma unroll
    for (int off = 32; off > 0; off >>= 1) s += __shfl_down(s, off, 64);
    if (lane == 0) sl.inv[row] = 1.0f / sqrtf(s);
}

// ---------------- top-5 machinery ----------------
#define INSERT5(arr, v)                                                          \
    if ((v) > arr[4]) {                                                          \
        arr[4] = (v);                                                            \
        if (arr[4] > arr[3]) { float t_ = arr[4]; arr[4] = arr[3]; arr[3] = t_; }\
        if (arr[3] > arr[2]) { float t_ = arr[3]; arr[3] = arr[2]; arr[2] = t_; }\
        if (arr[2] > arr[1]) { float t_ = arr[2]; arr[2] = arr[1]; arr[1] = t_; }\
        if (arr[1] > arr[0]) { float t_ = arr[1]; arr[1] = arr[0]; arr[0] = t_; }\
    }

__device__ inline void topk_reduce_store(float top[KTOP], float (*buf)[KTOP], int t,
                                         float* feat, int q, int c0) {
    #pragma unroll
    for (int i = 0; i < KTOP; ++i) buf[t][i] = top[i];
    __syncthreads();
    for (int stride = 128; stride >= 1; stride >>= 1) {
        if (t < stride) {
            float arr[KTOP];
            #pragma unroll
            for (int i = 0; i < KTOP; ++i) arr[i] = buf[t][i];
            #pragma unroll
            for (int r = 0; r < KTOP; ++r) { float v = buf[t + stride][r]; INSERT5(arr, v); }
            #pragma unroll
            for (int i = 0; i < KTOP; ++i) buf[t][i] = arr[i];
        }
        __syncthreads();
    }
    if (t == 0) {
        float mx = buf[0][0];
        float sum = buf[0][0] + buf[0][1] + buf[0][2] + buf[0][3] + buf[0][4];
        feat[(long)q * 8 + c0] = mx;
        feat[(long)q * 8 + c0 + 1] = sum / (float)KTOP;
    }
}

// oh pool: S is doc_sim f32 [DLEN][QLEN], value = S[d][q]; y selects doc
__global__ void pool_oh(const float* __restrict__ S1, const float* __restrict__ S2,
                        float* __restrict__ feat1, float* __restrict__ feat2) {
    const float* S = blockIdx.y == 0 ? S1 : S2;
    float* feat = blockIdx.y == 0 ? feat1 : feat2;
    __shared__ float buf[256][KTOP];
    int q = blockIdx.x, t = threadIdx.x;
    float top[KTOP];
    #pragma unroll
    for (int i = 0; i < KTOP; ++i) top[i] = -3.4e38f;
    for (int d = t; d < DLEN; d += 256) {
        float v = S[(long)d * QLEN + q];
        INSERT5(top, v);
    }
    topk_reduce_store(top, buf, t, feat, q, 0);
}

// batched sim pools over 6 bf16 z-slices
struct PoolSlice { const float* qinv; const float* dinv; const int* dtok; float* feat; int mask; int c0; };
struct PoolArgs { PoolSlice s[6]; };

__global__ void pool_sim(const short* __restrict__ simbase, const int* __restrict__ qtok,
                         PoolArgs args) {
    PoolSlice sl;
    switch (blockIdx.y) {
        case 0: sl = args.s[0]; break; case 1: sl = args.s[1]; break;
        case 2: sl = args.s[2]; break; case 3: sl = args.s[3]; break;
        case 4: sl = args.s[4]; break; default: sl = args.s[5]; break;
    }
    __shared__ float buf[256][KTOP];
    int q = blockIdx.x, t = threadIdx.x;
    const short* S = simbase + (size_t)blockIdx.y * QLEN * DLEN + (size_t)q * DLEN;
    float qs = sl.qinv[q];
    bool qok = qtok[q] > 1;
    float top[KTOP];
    #pragma unroll
    for (int i = 0; i < KTOP; ++i) top[i] = -3.4e38f;
    for (int base = t * 8; base < DLEN; base += 2048) {
        short8v vv = *(const short8v*)(S + base);
        #pragma unroll
        for (int j = 0; j < 8; ++j) {
            float v = bf2f(vv[j]) * qs * sl.dinv[base + j];
            if (sl.mask && (!qok || sl.dtok[base + j] <= 1)) v = 0.f;
            INSERT5(top, v);
        }
    }
    topk_reduce_store(top, buf, t, sl.feat, q, sl.c0);
}

// ---------------- final MLP + reduce + loss ----------------
__global__ void final_score(const float* __restrict__ feat1, const float* __restrict__ feat2,
                            const float* __restrict__ w1, const float* __restrict__ b1,
                            const float* __restrict__ w2, const float* __restrict__ b2,
                            const float* __restrict__ a1p, const float* __restrict__ a2p,
                            float* __restrict__ out) {
    __shared__ float s1buf[256], s2buf[256];
    int q = threadIdx.x;
    float a1 = *a1p, a2 = *a2p;
    float v[2];
    #pragma unroll
    for (int dsel = 0; dsel < 2; ++dsel) {
        const float* feat = dsel == 0 ? feat1 : feat2;
        float x[8];
        #pragma unroll
        for (int i = 0; i < 8; ++i) x[i] = feat[q * 8 + i];
        float lo[8];
        #pragma unroll
        for (int j = 0; j < 8; ++j) {
            float s = b1[j];
            #pragma unroll
            for (int i = 0; i < 8; ++i) s += x[i] * w1[j * 8 + i];
            lo[j] = s >= 0.f ? s : a1 * s;
        }
        float s2v = b2[0];
        #pragma unroll
        for (int j = 0; j < 8; ++j) s2v += lo[j] * w2[j];
        v[dsel] = s2v >= 0.f ? s2v : a2 * s2v;
    }
    s1buf[q] = v[0];
    s2buf[q] = v[1];
    __syncthreads();
    for (int st = 128; st >= 1; st >>= 1) {
        if (q < st) { s1buf[q] += s1buf[q + st]; s2buf[q] += s2buf[q + st]; }
        __syncthreads();
    }
    if (q == 0) {
        float d1 = s1buf[0] / (float)QLEN;
        float d2 = s2buf[0] / (float)QLEN;
        float loss1 = fmaxf(0.f, -(d1 - d2) + 0.9f);
        out[0] = loss1; out[1] = d1; out[2] = d2; out[3] = loss1; out[4] = 0.f;
    }
}

extern "C" void kernel_launch(void* const* d_in, const int* in_sizes, int n_in,
                              void* d_out, int out_size, void* d_ws, size_t ws_size,
                              hipStream_t stream) {
    const int*   doc1     = (const int*)d_in[0];
    const int*   doc2     = (const int*)d_in[1];
    const int*   question = (const int*)d_in[2];
    const float* doc1_sim = (const float*)d_in[3];
    const float* doc2_sim = (const float*)d_in[4];
    const float* embeds   = (const float*)d_in[5];
    const float* filt_bi  = (const float*)d_in[6];
    const float* filt_tri = (const float*)d_in[7];
    const float* a_bi     = (const float*)d_in[8];
    const float* a_tri    = (const float*)d_in[9];
    const float* w1       = (const float*)d_in[10];
    const float* b1       = (const float*)d_in[11];
    const float* w2       = (const float*)d_in[12];
    const float* b2       = (const float*)d_in[13];
    const float* a1       = (const float*)d_in[14];
    const float* a2       = (const float*)d_in[15];
    float* out = (float*)d_out;

    float* ws = (float*)d_ws;
    size_t off = 0;
    auto allocf = [&](size_t n) { float* p = ws + off; off += n; return p; };
    float* feat1 = allocf(QLEN * 8);
    float* feat2 = allocf(QLEN * 8);
    float* qinv_e   = allocf(QLEN);
    float* qinv_bi  = allocf(QLEN);
    float* qinv_tri = allocf(QLEN);
    float* d1inv_e   = allocf(DLEN);
    float* d1inv_bi  = allocf(DLEN);
    float* d1inv_tri = allocf(DLEN);
    float* d2inv_e   = allocf(DLEN);
    float* d2inv_bi  = allocf(DLEN);
    float* d2inv_tri = allocf(DLEN);
    off = (off + 7) & ~(size_t)7;

    short* hb = (short*)(ws + off);
    size_t hoff = 0;
    auto alloch = [&](size_t n) { short* p = hb + hoff; hoff += n; return p; };
    const size_t QH = (size_t)(QLEN + 8) * STR;
    const size_t DH = (size_t)(DLEN + 8) * STR;
    const size_t SIMN = (size_t)QLEN * DLEN;
    short* qe_h   = alloch(QH);
    short* qbi_h  = alloch(QH);
    short* qtri_h = alloch(QH);
    short* d1e_h   = alloch(DH);
    short* d1bi_h  = alloch(DH);
    short* d1tri_h = alloch(DH);
    short* d2e_h   = alloch(DH);
    short* d2bi_h  = alloch(DH);
    short* d2tri_h = alloch(DH);
    short* fbi_h  = alloch((size_t)384 * 2 * STR);   // flat [384][2*320]
    short* ftri_h = alloch((size_t)384 * 3 * STR);   // flat [384][3*320]
    short* simb   = alloch(SIMN * 6);

    // gathers + filter casts (cover pads; no memset)
    GatherArgs ga;
    ga.toks[0] = question; ga.out[0] = qe_h;  ga.rows[0] = QLEN;
    ga.toks[1] = doc1;     ga.out[1] = d1e_h; ga.rows[1] = DLEN;
    ga.toks[2] = doc2;     ga.out[2] = d2e_h; ga.rows[2] = DLEN;
    gather_cast<<<dim3(2048, 3), 256, 0, stream>>>(embeds, ga);

    FiltArgs fa;
    fa.f[0] = filt_bi;  fa.out[0] = fbi_h;  fa.fs[0] = 2;
    fa.f[1] = filt_tri; fa.out[1] = ftri_h; fa.fs[1] = 3;
    cast_filt<<<dim3(512, 2), 256, 0, stream>>>(fa);

    // conv GEMMs (flat-K; bi: fs=2 shift=1; tri: fs=3 shift=0); 3*64*6 = 1152 blocks
    ConvArgs ca;
    ca.s[0] = { qe_h,  fbi_h,  qbi_h,  a_bi,  QLEN, 2, 1 };
    ca.s[1] = { qe_h,  ftri_h, qtri_h, a_tri, QLEN, 3, 0 };
    ca.s[2] = { d1e_h, fbi_h,  d1bi_h, a_bi,  DLEN, 2, 1 };
    ca.s[3] = { d1e_h, ftri_h, d1tri_h,a_tri, DLEN, 3, 0 };
    ca.s[4] = { d2e_h, fbi_h,  d2bi_h, a_bi,  DLEN, 2, 1 };
    ca.s[5] = { d2e_h, ftri_h, d2tri_h,a_tri, DLEN, 3, 0 };
    conv_mfma<<<dim3(1152), 256, 0, stream>>>(ca);

    // batched inverse norms
    InvArgs ia;
    ia.s[0] = { qe_h,   qinv_e,   QLEN };
    ia.s[1] = { qbi_h,  qinv_bi,  QLEN };
    ia.s[2] = { qtri_h, qinv_tri, QLEN };
    ia.s[3] = { d1e_h,   d1inv_e,   DLEN };
    ia.s[4] = { d1bi_h,  d1inv_bi,  DLEN };
    ia.s[5] = { d1tri_h, d1inv_tri, DLEN };
    ia.s[6] = { d2e_h,   d2inv_e,   DLEN };
    ia.s[7] = { d2bi_h,  d2inv_bi,  DLEN };
    ia.s[8] = { d2tri_h, d2inv_tri, DLEN };
    inv_norms<<<dim3(2048, 9), 256, 0, stream>>>(ia);

    // oh pools (f32 inputs)
    pool_oh<<<dim3(QLEN, 2), 256, 0, stream>>>(doc1_sim, doc2_sim, feat1, feat2);

    // all 6 sim GEMMs in one launch; 64*2*6 = 768 blocks
    SimArgs sa;
    sa.s[0] = { qe_h,   d1e_h,   simb };
    sa.s[1] = { qbi_h,  d1bi_h,  simb + SIMN };
    sa.s[2] = { qtri_h, d1tri_h, simb + 2 * SIMN };
    sa.s[3] = { qe_h,   d2e_h,   simb + 3 * SIMN };
    sa.s[4] = { qbi_h,  d2bi_h,  simb + 4 * SIMN };
    sa.s[5] = { qtri_h, d2tri_h, simb + 5 * SIMN };
    sim_mfma<<<dim3(768), 256, 0, stream>>>(sa);

    // all 6 sim pools in one launch
    PoolArgs pa;
    pa.s[0] = { qinv_e,   d1inv_e,   doc1, feat1, 1, 2 };
    pa.s[1] = { qinv_bi,  d1inv_bi,  doc1, feat1, 0, 4 };
    pa.s[2] = { qinv_tri, d1inv_tri, doc1, feat1, 0, 6 };
    pa.s[3] = { qinv_e,   d2inv_e,   doc2, feat2, 1, 2 };
    pa.s[4] = { qinv_bi,  d2inv_bi,  doc2, feat2, 0, 4 };
    pa.s[5] = { qinv_tri, d2inv_tri, doc2, feat2, 0, 6 };
    pool_sim<<<dim3(QLEN, 6), 256, 0, stream>>>(simb, question, pa);

    final_score<<<dim3(1), 256, 0, stream>>>(feat1, feat2, w1, b1, w2, b2, a1, a2, out);
}